// Round 12
// baseline (348.698 us; speedup 1.0000x reference)
//
#include <hip/hip_runtime.h>
#include <hip/hip_bf16.h>

#define C_CH 512
#define HW 16384
#define NB 8
#define TILE 128
#define NTB 4
#define NTILES 10                 // upper-triangular 128^2 tiles
#define KSPLIT 8
#define KCHUNK (HW / KSPLIT)      // 2048
#define NGRAM 16
#define CC (C_CH * C_CH)
#define LOSS_BLOCKS 1024
#define GRID (NGRAM * KSPLIT * NTILES)   // 1280 = 8 XCDs * 160

// bf16 path
#define BKB 64                    // bf16 k-elements per K-step (2 MFMA k-subs)
#define KSTEPS_B (KCHUNK / BKB)   // 32
// f32 fallback path
#define BKF 32
#define KSTEPS_F (KCHUNC_F)
#define KCHUNC_F (KCHUNK / BKF)   // 64
#define PANEL_V8 (TILE * BKF / 8) // 512 bf16x8 slots = 8 KiB (fallback)

#define TOT_ELEMS 134217728LL     // 2 tensors * 8 * 512 * 16384
#define HALF_ELEMS 67108864LL

typedef float f32x4 __attribute__((ext_vector_type(4)));
typedef float f32x8 __attribute__((ext_vector_type(8)));
typedef __bf16 bf16x8 __attribute__((ext_vector_type(8)));

#define GLOAD_LDS16(gsrc, ldst)                                                 \
    __builtin_amdgcn_global_load_lds(                                           \
        (const __attribute__((address_space(1))) void*)(gsrc),                  \
        (__attribute__((address_space(3))) void*)(ldst), 16, 0, 0)

#define BAR_LGKM()                                                  \
    do {                                                            \
        asm volatile("s_waitcnt lgkmcnt(0)" ::: "memory");          \
        __builtin_amdgcn_s_barrier();                               \
        asm volatile("" ::: "memory");                              \
    } while (0)

// ---------------------------------------------------------------------------
// Pass 1: sequential f32 -> bf16 stream (the only pattern that saturates HBM).
__global__ __launch_bounds__(256) void convert_kernel(const float* __restrict__ det,
                                                      const float* __restrict__ sr,
                                                      __bf16* __restrict__ bf) {
    const long long stride = (long long)gridDim.x * 256 * 8;
    for (long long i = ((long long)blockIdx.x * 256 + threadIdx.x) * 8;
         i < TOT_ELEMS; i += stride) {
        const float* src = (i < HALF_ELEMS) ? det + i : sr + (i - HALF_ELEMS);
        f32x4 lo = *(const f32x4*)src;
        f32x4 hi = *(const f32x4*)(src + 4);
        bf16x8 h;
        #pragma unroll
        for (int k = 0; k < 4; ++k) { h[k] = (__bf16)lo[k]; h[4 + k] = (__bf16)hi[k]; }
        *(bf16x8*)(bf + i) = h;
    }
}

// ---------------------------------------------------------------------------
// Pass 2: Gram SYRK from bf16 copy. 128^2 triangular tiles, 4 waves (2x2),
// 2 blocks/CU, global_load_lds staging (linear dest + XOR-involution source),
// counted-vmcnt 2-phase, single ds_read_b128 per fragment (no cvt in loop).
__global__ __launch_bounds__(256, 2) void gram_bf16_kernel(const __bf16* __restrict__ bf,
                                                           float* __restrict__ gram) {
    const int bid = (int)blockIdx.x;
    const int lbid = (bid & 7) * (GRID / 8) + (bid >> 3);   // XCD grouping
    const int t = lbid % NTILES;
    const int gk = lbid / NTILES;
    const int ks = gk & (KSPLIT - 1);
    const int g = gk >> 3;

    int ti = 0, tt = t;
    while (tt >= NTB - ti) { tt -= NTB - ti; ++ti; }
    const int tj = ti + tt;
    const bool diag = (ti == tj);

    const __bf16* F = bf + (size_t)g * C_CH * HW;
    const __bf16* Abase = F + (size_t)(ti * TILE) * HW + ks * KCHUNK;
    const __bf16* Bbase = F + (size_t)(tj * TILE) * HW + ks * KCHUNK;

    __shared__ bf16x8 lds[2][2][1024];   // [buf][A,B][row*8+slot] = 64 KiB

    const int tid = threadIdx.x;
    const int lane = tid & 63;
    const int wid = tid >> 6;
    const int wr = wid >> 1, wc = wid & 1;   // 2x2 waves -> per-wave 64x64
    const int kg = lane >> 4;
    const int l15 = lane & 15;

    // STAGE: LDS linear in f (HW rule); logical (row R=f>>3, slot s=f&7) holds
    // global 16B-chunk c = s ^ (R&7); fragment read applies the same XOR.
    auto STAGE = [&](int buf, int kt) {
        const __bf16* sA = Abase + kt * BKB;
        #pragma unroll
        for (int q = 0; q < 4; ++q) {
            int f = q * 256 + tid;
            int R = f >> 3, s = f & 7;
            int c = s ^ (R & 7);
            GLOAD_LDS16(sA + (size_t)R * HW + c * 8, &lds[buf][0][f]);
        }
        if (!diag) {
            const __bf16* sB = Bbase + kt * BKB;
            #pragma unroll
            for (int q = 0; q < 4; ++q) {
                int f = q * 256 + tid;
                int R = f >> 3, s = f & 7;
                int c = s ^ (R & 7);
                GLOAD_LDS16(sB + (size_t)R * HW + c * 8, &lds[buf][1][f]);
            }
        }
    };

    f32x4 acc[4][4] = {};
    auto COMPUTE = [&](int buf) {
        const bf16x8* As = &lds[buf][0][0];
        const bf16x8* Bs = diag ? As : &lds[buf][1][0];
        #pragma unroll
        for (int ksub = 0; ksub < 2; ++ksub) {
            bf16x8 af[4], bfr[4];
            #pragma unroll
            for (int m = 0; m < 4; ++m) {
                int R = wr * 64 + m * 16 + l15;
                af[m] = As[R * 8 + ((ksub * 4 + kg) ^ (R & 7))];
            }
            #pragma unroll
            for (int n = 0; n < 4; ++n) {
                int R = wc * 64 + n * 16 + l15;
                bfr[n] = Bs[R * 8 + ((ksub * 4 + kg) ^ (R & 7))];
            }
            __builtin_amdgcn_s_setprio(1);
            #pragma unroll
            for (int m = 0; m < 4; ++m)
                #pragma unroll
                for (int n = 0; n < 4; ++n)
                    if (!diag || (wc * 64 + n * 16 + 16 > wr * 64 + m * 16))
                        acc[m][n] = __builtin_amdgcn_mfma_f32_16x16x32_bf16(af[m], bfr[n], acc[m][n], 0, 0, 0);
            __builtin_amdgcn_s_setprio(0);
        }
    };

    STAGE(0, 0);
    #pragma unroll 1
    for (int kt = 0; kt < KSTEPS_B; ++kt) {
        if (kt + 1 < KSTEPS_B) {
            STAGE((kt + 1) & 1, kt + 1);
            // drain stage(kt) only; stage(kt+1)'s 8 (4 diag) DMAs stay in flight
            if (diag) asm volatile("s_waitcnt vmcnt(4)" ::: "memory");
            else      asm volatile("s_waitcnt vmcnt(8)" ::: "memory");
        } else {
            asm volatile("s_waitcnt vmcnt(0)" ::: "memory");
        }
        __builtin_amdgcn_s_barrier();
        asm volatile("" ::: "memory");
        COMPUTE(kt & 1);
        BAR_LGKM();                      // reads done before next DMA overwrite
    }

    // epilogue: C/D layout col=lane&15, row=(lane>>4)*4+j; skip below-diag frags
    float* gout = gram + (size_t)g * CC;
    const int rb = ti * TILE + wr * 64 + (kg << 2);
    const int cb = tj * TILE + wc * 64 + l15;
    #pragma unroll
    for (int m = 0; m < 4; ++m)
        #pragma unroll
        for (int n = 0; n < 4; ++n) {
            if (diag && (wc * 64 + n * 16 + 16 <= wr * 64 + m * 16)) continue;
            #pragma unroll
            for (int j = 0; j < 4; ++j)
                atomicAdd(&gout[(size_t)(rb + m * 16 + j) * C_CH + cb + n * 16], acc[m][n][j]);
        }
}

// ---------------------------------------------------------------------------
// Fallback (ws too small): R7's proven f32 reg-staged gram (265-275 us).
__device__ __forceinline__ int slot_of(int R, int c) {
    return (R >> 1) * 8 + ((((R & 1) << 2) + c) ^ ((R >> 1) & 7));
}

__global__ __launch_bounds__(256, 2) void gram_f32_kernel(const float* __restrict__ det,
                                                          const float* __restrict__ sr,
                                                          float* __restrict__ gram) {
    const int lbid = ((int)blockIdx.x & 7) * (GRID / 8) + ((int)blockIdx.x >> 3);
    const int t = lbid % NTILES;
    const int gk = lbid / NTILES;
    const int ks = gk & (KSPLIT - 1);
    const int g = gk >> 3;
    const int tensor = g >> 3, b = g & 7;

    int ti = 0, tt = t;
    while (tt >= NTB - ti) { tt -= NTB - ti; ++ti; }
    const int tj = ti + tt;
    const bool diag = (ti == tj);

    const float* F = (tensor ? sr : det) + (size_t)b * C_CH * HW;
    const float* Abase = F + (size_t)(ti * TILE) * HW + ks * KCHUNK;
    const float* Bbase = F + (size_t)(tj * TILE) * HW + ks * KCHUNK;

    __shared__ bf16x8 lds[4 * PANEL_V8];

    const int tid = threadIdx.x;
    const int lane = tid & 63;
    const int wid = tid >> 6;
    const int wr = wid >> 1, wc = wid & 1;

    int goff[2], lslot[2];
    #pragma unroll
    for (int q = 0; q < 2; ++q) {
        int c = q * 256 + tid;
        int r = c >> 2, ch = c & 3;
        goff[q] = r * HW + ch * 8;
        lslot[q] = slot_of(r, ch);
    }

    f32x8 va[2], vb[2];
    auto LOAD = [&](int kt) {
        const int ko = kt * BKF;
        #pragma unroll
        for (int q = 0; q < 2; ++q) va[q] = *(const f32x8*)(Abase + goff[q] + ko);
        if (!diag) {
            #pragma unroll
            for (int q = 0; q < 2; ++q) vb[q] = *(const f32x8*)(Bbase + goff[q] + ko);
        }
    };
    auto WRITE = [&](int buf) {
        bf16x8* As = lds + buf * 2 * PANEL_V8;
        #pragma unroll
        for (int q = 0; q < 2; ++q) {
            bf16x8 h;
            #pragma unroll
            for (int i = 0; i < 8; ++i) h[i] = (__bf16)va[q][i];
            As[lslot[q]] = h;
        }
        if (!diag) {
            bf16x8* Bs = As + PANEL_V8;
            #pragma unroll
            for (int q = 0; q < 2; ++q) {
                bf16x8 h;
                #pragma unroll
                for (int i = 0; i < 8; ++i) h[i] = (__bf16)vb[q][i];
                Bs[lslot[q]] = h;
            }
        }
    };

    f32x4 acc[4][4] = {};
    const int kg = lane >> 4;
    const int l15 = lane & 15;
    auto COMPUTE = [&](const bf16x8* As) {
        const bf16x8* Bs = diag ? As : As + PANEL_V8;
        bf16x8 af[4], bfr[4];
        #pragma unroll
        for (int m = 0; m < 4; ++m) af[m] = As[slot_of(wr * 64 + m * 16 + l15, kg)];
        #pragma unroll
        for (int n = 0; n < 4; ++n) bfr[n] = Bs[slot_of(wc * 64 + n * 16 + l15, kg)];
        #pragma unroll
        for (int m = 0; m < 4; ++m)
            #pragma unroll
            for (int n = 0; n < 4; ++n)
                if (!diag || (wc * 64 + n * 16 + 16 > wr * 64 + m * 16))
                    acc[m][n] = __builtin_amdgcn_mfma_f32_16x16x32_bf16(af[m], bfr[n], acc[m][n], 0, 0, 0);
    };

    LOAD(0);
    WRITE(0);
    __syncthreads();
    int cur = 0;
    #pragma unroll 1
    for (int kt = 0; kt < 64; ++kt) {
        if (kt + 1 < 64) LOAD(kt + 1);
        COMPUTE(lds + cur * 2 * PANEL_V8);
        if (kt + 1 < 64) WRITE(cur ^ 1);
        __syncthreads();
        cur ^= 1;
    }

    float* gout = gram + (size_t)g * CC;
    const int rb = ti * TILE + wr * 64 + (kg << 2);
    const int cb = tj * TILE + wc * 64 + l15;
    #pragma unroll
    for (int m = 0; m < 4; ++m)
        #pragma unroll
        for (int n = 0; n < 4; ++n) {
            if (diag && (wc * 64 + n * 16 + 16 <= wr * 64 + m * 16)) continue;
            #pragma unroll
            for (int j = 0; j < 4; ++j)
                atomicAdd(&gout[(size_t)(rb + m * 16 + j) * C_CH + cb + n * 16], acc[m][n][j]);
        }
}

// ---------------------------------------------------------------------------
__global__ void norm_kernel(const float* __restrict__ gram, float* __restrict__ invn) {
    const int g = blockIdx.x, c = threadIdx.x;
    float v = gram[(size_t)g * CC + (size_t)c * C_CH + c];
    invn[g * C_CH + c] = 1.0f / sqrtf(v);
}

__global__ __launch_bounds__(256) void loss_kernel(const float* __restrict__ gram,
                                                   const float* __restrict__ invn,
                                                   float* __restrict__ partials) {
    const int tid = threadIdx.x;
    float s = 0.f;
    for (int idx = blockIdx.x * 256 + tid; idx < NB * CC; idx += LOSS_BLOCKS * 256) {
        int b = idx >> 18;
        int c = (idx >> 9) & 511;
        int d = idx & 511;
        int cc = c, dd = d;
        if (dd < cc) { int tmp = cc; cc = dd; dd = tmp; }
        float gd = gram[(size_t)b * CC + (size_t)cc * C_CH + dd];
        float gs = gram[(size_t)(8 + b) * CC + (size_t)cc * C_CH + dd];
        float sd = gd * invn[b * C_CH + c] * invn[b * C_CH + d];
        float ss = gs * invn[(8 + b) * C_CH + c] * invn[(8 + b) * C_CH + d];
        float diff = sd - ss;
        s += diff * diff;
    }
    #pragma unroll
    for (int off = 32; off > 0; off >>= 1) s += __shfl_down(s, off, 64);
    __shared__ float red[4];
    if ((tid & 63) == 0) red[tid >> 6] = s;
    __syncthreads();
    if (tid == 0) partials[blockIdx.x] = red[0] + red[1] + red[2] + red[3];
}

__global__ void final_kernel(const float* __restrict__ partials, float* __restrict__ out) {
    const int tid = threadIdx.x;
    float s = 0.f;
    for (int i = tid; i < LOSS_BLOCKS; i += 256) s += partials[i];
    #pragma unroll
    for (int off = 32; off > 0; off >>= 1) s += __shfl_down(s, off, 64);
    __shared__ float red[4];
    if ((tid & 63) == 0) red[tid >> 6] = s;
    __syncthreads();
    if (tid == 0) out[0] = (red[0] + red[1] + red[2] + red[3]) * (1.0f / (float)(NB * (size_t)CC));
}

extern "C" void kernel_launch(void* const* d_in, const int* in_sizes, int n_in,
                              void* d_out, int out_size, void* d_ws, size_t ws_size,
                              hipStream_t stream) {
    const float* det = (const float*)d_in[0];
    const float* sr  = (const float*)d_in[1];
    float* out = (float*)d_out;

    const size_t bf_bytes   = (size_t)TOT_ELEMS * 2;               // 256 MiB
    const size_t gram_bytes = (size_t)NGRAM * CC * sizeof(float);  // 16.8 MB
    const size_t aux_bytes  = (NGRAM * C_CH + LOSS_BLOCKS) * sizeof(float);

    if (ws_size >= bf_bytes + gram_bytes + aux_bytes) {
        __bf16* bfp     = (__bf16*)d_ws;
        float* gram     = (float*)((char*)d_ws + bf_bytes);
        float* invn     = gram + (size_t)NGRAM * CC;
        float* partials = invn + NGRAM * C_CH;

        convert_kernel<<<2048, 256, 0, stream>>>(det, sr, bfp);
        hipMemsetAsync(gram, 0, gram_bytes, stream);
        gram_bf16_kernel<<<GRID, 256, 0, stream>>>(bfp, gram);
        norm_kernel<<<NGRAM, C_CH, 0, stream>>>(gram, invn);
        loss_kernel<<<LOSS_BLOCKS, 256, 0, stream>>>(gram, invn, partials);
        final_kernel<<<1, 256, 0, stream>>>(partials, out);
    } else {
        float* gram     = (float*)d_ws;
        float* invn     = gram + (size_t)NGRAM * CC;
        float* partials = invn + NGRAM * C_CH;

        hipMemsetAsync(gram, 0, gram_bytes, stream);
        gram_f32_kernel<<<GRID, 256, 0, stream>>>(det, sr, gram);
        norm_kernel<<<NGRAM, C_CH, 0, stream>>>(gram, invn);
        loss_kernel<<<LOSS_BLOCKS, 256, 0, stream>>>(gram, invn, partials);
        final_kernel<<<1, 256, 0, stream>>>(partials, out);
    }
}

// Round 13
// 347.761 us; speedup vs baseline: 1.0027x; 1.0027x over previous
//
#include <hip/hip_runtime.h>
#include <hip/hip_bf16.h>

#define C_CH 512
#define HW 16384
#define NB 8
#define TILE 256
#define BK 32                     // f32 k-elements per K-step (= MFMA K in bf16)
#define NTILES 3                  // (0,0),(0,1),(1,1)
#define KSPLIT 16
#define KCHUNK (HW / KSPLIT)      // 1024
#define KSTEPS (KCHUNK / BK)      // 32
#define NGRAM 16
#define CC (C_CH * C_CH)
#define LOSS_BLOCKS 1024
#define GRID (NGRAM * KSPLIT * NTILES)   // 768 = 8 XCDs * 96
#define PANEL_SLOTS (TILE * 8)           // 2048 f32x4 = 32 KiB per panel

typedef float f32x4 __attribute__((ext_vector_type(4)));
typedef __bf16 bf16x8 __attribute__((ext_vector_type(8)));

#define GLOAD_LDS16(gsrc, ldst)                                                 \
    __builtin_amdgcn_global_load_lds(                                           \
        (const __attribute__((address_space(1))) void*)(gsrc),                  \
        (__attribute__((address_space(3))) void*)(ldst), 16, 0, 0)

// Gram SYRK, single pass from f32: 256^2 triangular tiles (2x panel-read
// amplification vs 4x at 128^2 -- aggregate vector-memory service measured
// ~7.7 TB/s across R1-R12, so time ~ issued bytes), 8 waves (2x4),
// global_load_lds staging (linear LDS dest + XOR-involution global source),
// counted-vmcnt 2-phase pipeline (R12-proven engine), cvt f32->bf16 at
// fragment read.
__global__ __launch_bounds__(512) void gram_kernel(const float* __restrict__ det,
                                                   const float* __restrict__ sr,
                                                   float* __restrict__ gram) {
    // XCD clustering (R10): xcd X serves grams 2X,2X+1; the 3 tiles of each
    // (g,ks) are consecutive -> co-resident -> L2 serves the 2x panel reuse
    const int bid = (int)blockIdx.x;
    const int idx = bid >> 3;            // 0..95 within XCD
    const int g = (bid & 7) * 2 + idx / 48;
    const int rem = idx % 48;
    const int ks = rem / 3;
    const int t = rem % 3;
    const int tensor = g >> 3, b = g & 7;
    const int ti = (t == 2) ? 1 : 0;
    const int tj = (t == 0) ? 0 : 1;
    const bool diag = (t != 1);

    const float* F = (tensor ? sr : det) + (size_t)b * C_CH * HW;
    const float* Abase = F + (size_t)(ti * TILE) * HW + ks * KCHUNK;
    const float* Bbase = F + (size_t)(tj * TILE) * HW + ks * KCHUNK;

    __shared__ f32x4 lds[2][2][PANEL_SLOTS];   // [buf][A,B] = 128 KiB

    const int tid = threadIdx.x;
    const int lane = tid & 63;
    const int wid = tid >> 6;
    const int wr = wid >> 2, wc = wid & 3;   // 2x4 waves -> per-wave 128x64
    const int kg = lane >> 4;                // quarter-wave k-chunk pair selector
    const int l15 = lane & 15;

    // STAGE: LDS dest LINEAR in f (wave-uniform base + lane*16 -- HW rule);
    // logical (row R=f>>3, slot s=f&7) holds global 16B-chunk c = s ^ (R&7)
    // (involution; fragment read applies the same XOR).
    auto STAGE = [&](int buf, int kt) {
        const float* sA = Abase + kt * BK;
        #pragma unroll
        for (int q = 0; q < 4; ++q) {
            int f = q * 512 + tid;
            int R = f >> 3, s = f & 7;
            int c = s ^ (R & 7);
            GLOAD_LDS16(sA + (size_t)R * HW + c * 4, &lds[buf][0][f]);
        }
        if (!diag) {
            const float* sB = Bbase + kt * BK;
            #pragma unroll
            for (int q = 0; q < 4; ++q) {
                int f = q * 512 + tid;
                int R = f >> 3, s = f & 7;
                int c = s ^ (R & 7);
                GLOAD_LDS16(sB + (size_t)R * HW + c * 4, &lds[buf][1][f]);
            }
        }
    };

    // fragment read: 8 f32 of k-range kg*8..kg*8+7 from chunks 2kg,2kg+1
    // (XOR-inverted), cvt to bf16x8. Per quarter-wave: 2 lanes/bank-group = free.
    auto rdfrag = [&](const f32x4* P, int R) {
        f32x4 lo = P[R * 8 + ((2 * kg) ^ (R & 7))];
        f32x4 hi = P[R * 8 + ((2 * kg + 1) ^ (R & 7))];
        bf16x8 h;
        #pragma unroll
        for (int i = 0; i < 4; ++i) { h[i] = (__bf16)lo[i]; h[4 + i] = (__bf16)hi[i]; }
        return h;
    };

    f32x4 acc[8][4] = {};
    auto COMPUTE = [&](int buf) {
        const f32x4* As = &lds[buf][0][0];
        const f32x4* Bs = diag ? As : &lds[buf][1][0];
        bf16x8 af[8], bfr[4];
        #pragma unroll
        for (int m = 0; m < 8; ++m) af[m] = rdfrag(As, wr * 128 + m * 16 + l15);
        #pragma unroll
        for (int n = 0; n < 4; ++n) bfr[n] = rdfrag(Bs, wc * 64 + n * 16 + l15);
        __builtin_amdgcn_s_setprio(1);
        #pragma unroll
        for (int m = 0; m < 8; ++m)
            #pragma unroll
            for (int n = 0; n < 4; ++n)
                if (!diag || (wc * 64 + n * 16 + 16 > wr * 128 + m * 16))
                    acc[m][n] = __builtin_amdgcn_mfma_f32_16x16x32_bf16(af[m], bfr[n], acc[m][n], 0, 0, 0);
        __builtin_amdgcn_s_setprio(0);
    };

    // 2-phase pipeline with counted vmcnt (R12-proven): stage(kt+1) issued
    // before waiting on stage(kt); its DMAs stay in flight across barriers.
    STAGE(0, 0);
    #pragma unroll 1
    for (int kt = 0; kt < KSTEPS; ++kt) {
        if (kt + 1 < KSTEPS) {
            STAGE((kt + 1) & 1, kt + 1);
            if (diag) asm volatile("s_waitcnt vmcnt(4)" ::: "memory");
            else      asm volatile("s_waitcnt vmcnt(8)" ::: "memory");
        } else {
            asm volatile("s_waitcnt vmcnt(0)" ::: "memory");
        }
        __builtin_amdgcn_s_barrier();
        asm volatile("" ::: "memory");
        COMPUTE(kt & 1);
        asm volatile("s_waitcnt lgkmcnt(0)" ::: "memory");   // frag reads done
        __builtin_amdgcn_s_barrier();                        // before next overwrite
        asm volatile("" ::: "memory");
    }

    // epilogue: C/D layout col=lane&15, row=(lane>>4)*4+j; skip below-diag frags
    float* gout = gram + (size_t)g * CC;
    const int rb = ti * TILE + wr * 128 + (kg << 2);
    const int cb = tj * TILE + wc * 64 + l15;
    #pragma unroll
    for (int m = 0; m < 8; ++m)
        #pragma unroll
        for (int n = 0; n < 4; ++n) {
            if (diag && (wc * 64 + n * 16 + 16 <= wr * 128 + m * 16)) continue;
            #pragma unroll
            for (int j = 0; j < 4; ++j)
                atomicAdd(&gout[(size_t)(rb + m * 16 + j) * C_CH + cb + n * 16], acc[m][n][j]);
        }
}

__global__ void norm_kernel(const float* __restrict__ gram, float* __restrict__ invn) {
    const int g = blockIdx.x, c = threadIdx.x;
    float v = gram[(size_t)g * CC + (size_t)c * C_CH + c];
    invn[g * C_CH + c] = 1.0f / sqrtf(v);
}

__global__ __launch_bounds__(256) void loss_kernel(const float* __restrict__ gram,
                                                   const float* __restrict__ invn,
                                                   float* __restrict__ partials) {
    const int tid = threadIdx.x;
    float s = 0.f;
    for (int idx = blockIdx.x * 256 + tid; idx < NB * CC; idx += LOSS_BLOCKS * 256) {
        int b = idx >> 18;
        int c = (idx >> 9) & 511;
        int d = idx & 511;
        int cc = c, dd = d;
        if (dd < cc) { int tmp = cc; cc = dd; dd = tmp; }   // upper triangle stored
        float gd = gram[(size_t)b * CC + (size_t)cc * C_CH + dd];
        float gs = gram[(size_t)(8 + b) * CC + (size_t)cc * C_CH + dd];
        float sd = gd * invn[b * C_CH + c] * invn[b * C_CH + d];
        float ss = gs * invn[(8 + b) * C_CH + c] * invn[(8 + b) * C_CH + d];
        float diff = sd - ss;
        s += diff * diff;
    }
    #pragma unroll
    for (int off = 32; off > 0; off >>= 1) s += __shfl_down(s, off, 64);
    __shared__ float red[4];
    if ((tid & 63) == 0) red[tid >> 6] = s;
    __syncthreads();
    if (tid == 0) partials[blockIdx.x] = red[0] + red[1] + red[2] + red[3];
}

__global__ void final_kernel(const float* __restrict__ partials, float* __restrict__ out) {
    const int tid = threadIdx.x;  // 256
    float s = 0.f;
    for (int i = tid; i < LOSS_BLOCKS; i += 256) s += partials[i];
    #pragma unroll
    for (int off = 32; off > 0; off >>= 1) s += __shfl_down(s, off, 64);
    __shared__ float red[4];
    if ((tid & 63) == 0) red[tid >> 6] = s;
    __syncthreads();
    if (tid == 0) out[0] = (red[0] + red[1] + red[2] + red[3]) * (1.0f / (float)(NB * (size_t)CC));
}

extern "C" void kernel_launch(void* const* d_in, const int* in_sizes, int n_in,
                              void* d_out, int out_size, void* d_ws, size_t ws_size,
                              hipStream_t stream) {
    const float* det = (const float*)d_in[0];
    const float* sr  = (const float*)d_in[1];
    float* gram     = (float*)d_ws;                       // 16 * 512 * 512 f32 = 16.78 MB
    float* invn     = gram + (size_t)NGRAM * CC;
    float* partials = invn + NGRAM * C_CH;
    float* out      = (float*)d_out;

    hipMemsetAsync(gram, 0, (size_t)NGRAM * CC * sizeof(float), stream);
    gram_kernel<<<GRID, 512, 0, stream>>>(det, sr, gram);
    norm_kernel<<<NGRAM, C_CH, 0, stream>>>(gram, invn);
    loss_kernel<<<LOSS_BLOCKS, 256, 0, stream>>>(gram, invn, partials);
    final_kernel<<<1, 256, 0, stream>>>(partials, out);
}